// Round 3
// baseline (1173.081 us; speedup 1.0000x reference)
//
#include <hip/hip_runtime.h>
#include <cstdint>
#include <cstddef>

typedef __attribute__((ext_vector_type(8))) short short8;
typedef __attribute__((ext_vector_type(4))) float f32x4;

#define MFMA16(a, b, c) __builtin_amdgcn_mfma_f32_16x16x32_bf16((a), (b), (c), 0, 0, 0)

constexpr int kB = 512, kS = 256, kI = 12, kH = 256, kA = 9;
constexpr int kNS = 8;    // hidden slices per batch tile (32 h-units each)
constexpr int kNB = 32;   // batch tiles (16 rows each)
constexpr int LDH = 264;  // padded LDS stride (bf16) for K=256 operand tiles
constexpr int LDG = 132;  // padded LDS stride (fp32) for 16x128 gate tiles
constexpr int kBH = kB * kH;
constexpr int FLS = 512;  // flag array stride per btile (ints) — keeps btiles on separate lines

// d_out layout (floats): [logits 512*9][h0 512*256][h1 512*256][c0 512*256][c1 512*256]
constexpr int OUT_H = kB * kA;              // 4608
constexpr int OUT_C = OUT_H + 2 * kBH;      // 266752

__device__ __forceinline__ short f2bf(float f) {  // RTNE fp32 -> bf16 bits
  uint32_t u = __float_as_uint(f);
  u += 0x7fffu + ((u >> 16) & 1u);
  return (short)(u >> 16);
}
__device__ __forceinline__ float fast_sigmoid(float v) {
  return __builtin_amdgcn_rcpf(1.f + __expf(-v));
}
__device__ __forceinline__ float fast_tanh(float v) {
  return 2.f * __builtin_amdgcn_rcpf(1.f + __expf(-2.f * v)) - 1.f;
}

// Persistent fused scan, PIPELINE-SKEWED: phase p computes layer0(step p) AND
// layer1(step p-1) — both depend only on data published at phase p-1 (h0(p-1)
// feeds both layer0's recurrence and layer1's input; h1(p-2) feeds layer1's
// recurrence). ONE publish->spin->gather IC round per phase (vs 2 in R2).
// All cross-wg traffic stays RELAXED agent-scope (no bulk L2 maintenance).
// Ordering: __syncthreads() drains vmcnt(0) before s_barrier, so exchange
// stores are IC-visible before tid0's flag add; readers poll the flag then load.
__global__ __launch_bounds__(256, 1) void lstm_scan_kernel(
    const float* __restrict__ x,
    const float* __restrict__ W_emb, const float* __restrict__ b_emb,
    const float* __restrict__ w_ih0, const float* __restrict__ w_hh0,
    const float* __restrict__ b_ih0, const float* __restrict__ b_hh0,
    const float* __restrict__ w_ih1, const float* __restrict__ w_hh1,
    const float* __restrict__ b_ih1, const float* __restrict__ b_hh1,
    unsigned short* __restrict__ h0ex, unsigned short* __restrict__ h1ex,
    int* __restrict__ flags,
    float* __restrict__ dout)
{
  const int tid   = threadIdx.x;
  const int btile = blockIdx.x & (kNB - 1);  // bid%32 -> slices of a btile share an XCD
  const int slice = blockIdx.x >> 5;
  const int b0    = btile * 16;
  const int lane  = tid & 63;
  const int wave  = tid >> 6;
  const int n16   = lane & 15;
  const int quad  = lane >> 4;

  __shared__ short embL[16 * LDH];   // emb(p) (bf16) A-operand
  __shared__ short hA[16 * LDH];     // h0(p-1) full — feeds layer0 recurrence AND layer1 input
  __shared__ short hB[16 * LDH];     // h1(p-2) full — feeds layer1 recurrence
  __shared__ float gL0[16 * LDG];    // layer0 gates 16 x 128 fp32
  __shared__ float gL1[16 * LDG];    // layer1 gates 16 x 128 fp32

  for (int i = tid; i < 16 * LDH; i += 256) { hA[i] = 0; hB[i] = 0; }

  // Weight B-fragments in registers: wave owns N-tiles {wave, wave+4} of the
  // slice's 128 gate cols. B-frag: lane(n=lane&15, quad) holds B[k=quad*8+j][n]
  // = weight row `gate_col` k-slice (weights are [4H, H] row-major).
  const float* Wm[4] = { w_ih0, w_hh0, w_ih1, w_hh1 };
  short8 wB[2][4][8];
#pragma unroll
  for (int ti = 0; ti < 2; ++ti) {
    const int nt   = wave + ti * 4;
    const int gcol = (nt >> 1) * kH + slice * 32 + (nt & 1) * 16 + n16;
#pragma unroll
    for (int mat = 0; mat < 4; ++mat) {
      const float* wp = Wm[mat] + (size_t)gcol * kH;
#pragma unroll
      for (int kk = 0; kk < 8; ++kk) {
        const float* p = wp + kk * 32 + quad * 8;
        const float4 f0 = *(const float4*)p;
        const float4 f1 = *(const float4*)(p + 4);
        short8 v;
        v[0] = f2bf(f0.x); v[1] = f2bf(f0.y); v[2] = f2bf(f0.z); v[3] = f2bf(f0.w);
        v[4] = f2bf(f1.x); v[5] = f2bf(f1.y); v[6] = f2bf(f1.z); v[7] = f2bf(f1.w);
        wB[ti][mat][kk] = v;
      }
    }
  }
  // Embedding weights (K=12 zero-padded to 32). Wave computes emb cols [wave*64, +64).
  short8 wE[4];
  float bembv[4];
#pragma unroll
  for (int i = 0; i < 4; ++i) {
    const int col = wave * 64 + i * 16 + n16;
    short8 v;
#pragma unroll
    for (int j = 0; j < 8; ++j) {
      const int k = quad * 8 + j;
      v[j] = (k < kI) ? f2bf(W_emb[col * kI + k]) : (short)0;
    }
    wE[i] = v;
    bembv[i] = b_emb[col];
  }
  // Elementwise mapping for COALESCED exchange stores: thread = (row=tid>>4,
  // col pair {2c, 2c+1}, c=tid&15) -> 16 consecutive lanes store 64B contiguous.
  const int erow = tid >> 4;
  const int ec   = (tid & 15) * 2;
  float bi0[2][4], bi1[2][4];
#pragma unroll
  for (int j = 0; j < 2; ++j) {
    const int col = slice * 32 + ec + j;
#pragma unroll
    for (int g = 0; g < 4; ++g) {
      bi0[j][g] = b_ih0[g * kH + col] + b_hh0[g * kH + col];
      bi1[j][g] = b_ih1[g * kH + col] + b_hh1[g * kH + col];
    }
  }
  float c0v[2] = {0.f, 0.f}, c1v[2] = {0.f, 0.f};

  // -------- prologue: emb(0) built from direct global x loads (no LDS staging) --------
  {
    const float* xr = x + (size_t)(b0 + n16) * kS * kI;  // t = 0
    short8 xa;
#pragma unroll
    for (int j = 0; j < 8; ++j) {
      const int k = quad * 8 + j;
      xa[j] = (k < kI) ? f2bf(xr[k]) : (short)0;
    }
#pragma unroll
    for (int i = 0; i < 4; ++i) {
      f32x4 z = {0.f, 0.f, 0.f, 0.f};
      f32x4 e = MFMA16(xa, wE[i], z);
      const int col = wave * 64 + i * 16 + n16;
#pragma unroll
      for (int r = 0; r < 4; ++r) {
        float v = e[r] + bembv[i];
        v = v > 0.f ? v : 0.f;
        embL[(quad * 4 + r) * LDH + col] = f2bf(v);  // C-layout: row=quad*4+r
      }
    }
  }
  __syncthreads();

  int* const fl = flags + btile * FLS;

  for (int p = 0; p <= kS; ++p) {
    const int par = p & 1;

    // ---- head: BOTH layers' gates, 64 independent MFMAs (hA frags shared).
    //      Edge phases (p=0: layer1; p=kS: layer0) compute don't-care values;
    //      only the elementwise state updates are guarded. ----
    {
      f32x4 a0 = {0.f,0.f,0.f,0.f}, a1 = a0, g1b0 = a0, g1b1 = a0;
#pragma unroll
      for (int kk = 0; kk < 8; ++kk) {
        const short8 ha = *(const short8*)&hA[n16 * LDH + kk * 32 + quad * 8];
        a0   = MFMA16(ha, wB[0][1][kk], a0);    // layer0 recurrent
        a1   = MFMA16(ha, wB[1][1][kk], a1);
        g1b0 = MFMA16(ha, wB[0][2][kk], g1b0);  // layer1 input (y0 = h0(p-1))
        g1b1 = MFMA16(ha, wB[1][2][kk], g1b1);
      }
#pragma unroll
      for (int kk = 0; kk < 8; ++kk) {
        const short8 e = *(const short8*)&embL[n16 * LDH + kk * 32 + quad * 8];
        a0 = MFMA16(e, wB[0][0][kk], a0);       // layer0 input
        a1 = MFMA16(e, wB[1][0][kk], a1);
      }
#pragma unroll
      for (int kk = 0; kk < 8; ++kk) {
        const short8 hb = *(const short8*)&hB[n16 * LDH + kk * 32 + quad * 8];
        g1b0 = MFMA16(hb, wB[0][3][kk], g1b0);  // layer1 recurrent
        g1b1 = MFMA16(hb, wB[1][3][kk], g1b1);
      }
#pragma unroll
      for (int ti = 0; ti < 2; ++ti) {
        const int nt = wave + ti * 4;
        const int lcol = (nt >> 1) * 32 + (nt & 1) * 16 + n16;
        const f32x4 va = ti ? a1 : a0;
        const f32x4 vb = ti ? g1b1 : g1b0;
#pragma unroll
        for (int r = 0; r < 4; ++r) {
          gL0[(quad * 4 + r) * LDG + lcol] = va[r];
          gL1[(quad * 4 + r) * LDG + lcol] = vb[r];
        }
      }
    }
    __syncthreads();  // B1: gate tiles ready

    // ---- elementwise layer0 (step p), guarded ----
    if (p < kS) {
      float hj[2];
#pragma unroll
      for (int j = 0; j < 2; ++j) {
        const int u = ec + j;
        const float iv = gL0[erow * LDG +       u] + bi0[j][0];
        const float fv = gL0[erow * LDG +  32 + u] + bi0[j][1];
        const float gv = gL0[erow * LDG +  64 + u] + bi0[j][2];
        const float ov = gL0[erow * LDG +  96 + u] + bi0[j][3];
        const float c = fast_sigmoid(fv) * c0v[j] + fast_sigmoid(iv) * fast_tanh(gv);
        c0v[j] = c;
        hj[j] = fast_sigmoid(ov) * fast_tanh(c);
      }
      const uint32_t pk = (uint32_t)(uint16_t)f2bf(hj[0]) |
                          ((uint32_t)(uint16_t)f2bf(hj[1]) << 16);
      uint32_t* dst = (uint32_t*)&h0ex[(size_t)par * kBH + (size_t)(b0 + erow) * kH + slice * 32 + ec];
      __hip_atomic_store(dst, pk, __ATOMIC_RELAXED, __HIP_MEMORY_SCOPE_AGENT);
      if (p == kS - 1) {
#pragma unroll
        for (int j = 0; j < 2; ++j) {
          const int col = slice * 32 + ec + j;
          dout[OUT_H + (size_t)(b0 + erow) * kH + col] = hj[j];
          dout[OUT_C + (size_t)(b0 + erow) * kH + col] = c0v[j];
        }
      }
    }
    // ---- elementwise layer1 (step p-1), guarded ----
    if (p >= 1) {
      float hj[2];
#pragma unroll
      for (int j = 0; j < 2; ++j) {
        const int u = ec + j;
        const float iv = gL1[erow * LDG +       u] + bi1[j][0];
        const float fv = gL1[erow * LDG +  32 + u] + bi1[j][1];
        const float gv = gL1[erow * LDG +  64 + u] + bi1[j][2];
        const float ov = gL1[erow * LDG +  96 + u] + bi1[j][3];
        const float c = fast_sigmoid(fv) * c1v[j] + fast_sigmoid(iv) * fast_tanh(gv);
        c1v[j] = c;
        hj[j] = fast_sigmoid(ov) * fast_tanh(c);
      }
      const uint32_t pk = (uint32_t)(uint16_t)f2bf(hj[0]) |
                          ((uint32_t)(uint16_t)f2bf(hj[1]) << 16);
      uint32_t* dst = (uint32_t*)&h1ex[(size_t)par * kBH + (size_t)(b0 + erow) * kH + slice * 32 + ec];
      __hip_atomic_store(dst, pk, __ATOMIC_RELAXED, __HIP_MEMORY_SCOPE_AGENT);
      if (p == kS) {
#pragma unroll
        for (int j = 0; j < 2; ++j) {
          const int col = slice * 32 + ec + j;
          dout[OUT_H + kBH + (size_t)(b0 + erow) * kH + col] = hj[j];
          dout[OUT_C + kBH + (size_t)(b0 + erow) * kH + col] = c1v[j];
        }
      }
    }
    __syncthreads();  // B2: drains vmcnt(0) -> exchange stores IC-visible

    if (p < kS) {
      // ---- publish (single flag per phase covers h0(p) AND h1(p-1)) ----
      if (tid == 0)
        __hip_atomic_fetch_add(fl + p, 1, __ATOMIC_RELAXED, __HIP_MEMORY_SCOPE_AGENT);

      // ---- emb(p+1): overlaps flag/data propagation through the IC ----
      if (p + 1 < kS) {
        const float* xr = x + ((size_t)(b0 + n16) * kS + (p + 1)) * kI;
        short8 xa;
#pragma unroll
        for (int j = 0; j < 8; ++j) {
          const int k = quad * 8 + j;
          xa[j] = (k < kI) ? f2bf(xr[k]) : (short)0;
        }
#pragma unroll
        for (int i = 0; i < 4; ++i) {
          f32x4 z = {0.f, 0.f, 0.f, 0.f};
          f32x4 e = MFMA16(xa, wE[i], z);
          const int col = wave * 64 + i * 16 + n16;
#pragma unroll
          for (int r = 0; r < 4; ++r) {
            float v = e[r] + bembv[i];
            v = v > 0.f ? v : 0.f;
            embL[(quad * 4 + r) * LDH + col] = f2bf(v);
          }
        }
      }

      // ---- all-thread spin (uniform exit; no tid0->barrier broadcast) ----
      while (__hip_atomic_load(fl + p, __ATOMIC_RELAXED, __HIP_MEMORY_SCOPE_AGENT) < kNS)
        __builtin_amdgcn_s_sleep(1);

      // ---- gather h0(p) -> hA, h1(p-1) -> hB (relaxed u64 loads, all issued first) ----
      {
        const int rr = tid >> 4;
        const int cc = (tid & 15) * 16;
        const size_t base = (size_t)par * kBH + (size_t)(b0 + rr) * kH + cc;
        const uint64_t* s0 = (const uint64_t*)&h0ex[base];
        const uint64_t* s1 = (const uint64_t*)&h1ex[base];
        uint64_t va0 = __hip_atomic_load(s0 + 0, __ATOMIC_RELAXED, __HIP_MEMORY_SCOPE_AGENT);
        uint64_t va1 = __hip_atomic_load(s0 + 1, __ATOMIC_RELAXED, __HIP_MEMORY_SCOPE_AGENT);
        uint64_t va2 = __hip_atomic_load(s0 + 2, __ATOMIC_RELAXED, __HIP_MEMORY_SCOPE_AGENT);
        uint64_t va3 = __hip_atomic_load(s0 + 3, __ATOMIC_RELAXED, __HIP_MEMORY_SCOPE_AGENT);
        uint64_t vb0 = __hip_atomic_load(s1 + 0, __ATOMIC_RELAXED, __HIP_MEMORY_SCOPE_AGENT);
        uint64_t vb1 = __hip_atomic_load(s1 + 1, __ATOMIC_RELAXED, __HIP_MEMORY_SCOPE_AGENT);
        uint64_t vb2 = __hip_atomic_load(s1 + 2, __ATOMIC_RELAXED, __HIP_MEMORY_SCOPE_AGENT);
        uint64_t vb3 = __hip_atomic_load(s1 + 3, __ATOMIC_RELAXED, __HIP_MEMORY_SCOPE_AGENT);
        uint64_t* dA = (uint64_t*)&hA[rr * LDH + cc];
        uint64_t* dB = (uint64_t*)&hB[rr * LDH + cc];
        dA[0] = va0; dA[1] = va1; dA[2] = va2; dA[3] = va3;
        dB[0] = vb0; dB[1] = vb1; dB[2] = vb2; dB[3] = vb3;
      }
      __syncthreads();  // B5: hA/hB/embL ready for next phase's head
    }
  }
}

// LayerNorm + MLP head, exact fp32. One wave per batch row.
__global__ __launch_bounds__(64) void head_kernel(
    const float* __restrict__ h1last, const float* __restrict__ mask,
    const float* __restrict__ ln_g, const float* __restrict__ ln_b,
    const float* __restrict__ w1, const float* __restrict__ b1,
    const float* __restrict__ w2, const float* __restrict__ b2,
    float* __restrict__ out)
{
  const int r = blockIdx.x;
  const int lane = threadIdx.x;
  __shared__ float ns[kH];
  __shared__ float hd[32];
  const float4 v = *(const float4*)&h1last[r * kH + lane * 4];
  float vv[4] = {v.x, v.y, v.z, v.w};
  float s = vv[0] + vv[1] + vv[2] + vv[3];
#pragma unroll
  for (int off = 32; off > 0; off >>= 1) s += __shfl_xor(s, off, 64);
  const float mean = s * (1.f / kH);
  float q = 0.f;
#pragma unroll
  for (int j = 0; j < 4; ++j) { const float d = vv[j] - mean; q += d * d; }
#pragma unroll
  for (int off = 32; off > 0; off >>= 1) q += __shfl_xor(q, off, 64);
  const float rstd = rsqrtf(q * (1.f / kH) + 1e-5f);
#pragma unroll
  for (int j = 0; j < 4; ++j) {
    const int c = lane * 4 + j;
    ns[c] = (vv[j] - mean) * rstd * ln_g[c] + ln_b[c];
  }
  __syncthreads();
  if (lane < 32) {
    float a = b1[lane];
    const float* wr = w1 + lane * kH;
    for (int k = 0; k < kH; ++k) a += ns[k] * wr[k];
    hd[lane] = a > 0.f ? a : 0.f;
  }
  __syncthreads();
  if (lane < kA) {
    float a = b2[lane];
    const float* wr = w2 + lane * 32;
#pragma unroll
    for (int k = 0; k < 32; ++k) a += hd[k] * wr[k];
    a += (1.f - mask[r * kA + lane]) * (-1e9f);
    out[r * kA + lane] = a;
  }
}

extern "C" void kernel_launch(void* const* d_in, const int* in_sizes, int n_in,
                              void* d_out, int out_size, void* d_ws, size_t ws_size,
                              hipStream_t stream)
{
  (void)in_sizes; (void)n_in; (void)out_size; (void)ws_size;
  const float* x     = (const float*)d_in[0];
  const float* mask  = (const float*)d_in[1];
  const float* W_emb = (const float*)d_in[2];
  const float* b_emb = (const float*)d_in[3];
  const float* w_ih0 = (const float*)d_in[4];
  const float* w_hh0 = (const float*)d_in[5];
  const float* b_ih0 = (const float*)d_in[6];
  const float* b_hh0 = (const float*)d_in[7];
  const float* w_ih1 = (const float*)d_in[8];
  const float* w_hh1 = (const float*)d_in[9];
  const float* b_ih1 = (const float*)d_in[10];
  const float* b_hh1 = (const float*)d_in[11];
  const float* ln_g  = (const float*)d_in[12];
  const float* ln_b  = (const float*)d_in[13];
  const float* w1    = (const float*)d_in[14];
  const float* b1    = (const float*)d_in[15];
  const float* w2    = (const float*)d_in[16];
  const float* b2    = (const float*)d_in[17];
  float* out = (float*)d_out;

  // ws layout: h0ex[2][512][256] bf16 | h1ex[2][512][256] bf16 | flags[32][512] int
  unsigned short* h0ex = (unsigned short*)d_ws;
  unsigned short* h1ex = h0ex + 2 * kBH;
  int* flags = (int*)(h1ex + 2 * kBH);
  const size_t flag_bytes = (size_t)kNB * FLS * sizeof(int);  // 64 KiB

  // flags must start at 0 (monotonic per-phase counters); h1ex parity-0 must be
  // zeros (h1(-1) = 0, gathered at phase 0). h0ex is always written before read.
  hipMemsetAsync(flags, 0, flag_bytes, stream);
  hipMemsetAsync(h1ex, 0, (size_t)kBH * sizeof(unsigned short), stream);

  lstm_scan_kernel<<<dim3(kNB * kNS), dim3(256), 0, stream>>>(
      x, W_emb, b_emb, w_ih0, w_hh0, b_ih0, b_hh0, w_ih1, w_hh1, b_ih1, b_hh1,
      h0ex, h1ex, flags, out);

  head_kernel<<<dim3(kB), dim3(64), 0, stream>>>(
      out + OUT_H + kBH, mask, ln_g, ln_b, w1, b1, w2, b2, out);
}

// Round 4
// 1011.539 us; speedup vs baseline: 1.1597x; 1.1597x over previous
//
#include <hip/hip_runtime.h>
#include <cstdint>
#include <cstddef>

typedef __attribute__((ext_vector_type(8))) short short8;
typedef __attribute__((ext_vector_type(4))) float f32x4;

#define MFMA16(a, b, c) __builtin_amdgcn_mfma_f32_16x16x32_bf16((a), (b), (c), 0, 0, 0)

constexpr int kB = 512, kS = 256, kI = 12, kH = 256, kA = 9;
constexpr int kNS = 8;    // hidden slices per batch tile (32 h-units each)
constexpr int kNB = 32;   // batch tiles (16 rows each)
constexpr int kT  = 512;  // block size: 8 waves -> 2 waves/SIMD (latency hiding)
constexpr int LDH = 264;  // padded LDS stride (bf16) for K=256 operand tiles
constexpr int LDG = 132;  // padded LDS stride (fp32) for 16x128 gate tiles
constexpr int kBH = kB * kH;
constexpr int FLS = 512;  // flag array stride per btile (ints)

// d_out layout (floats): [logits 512*9][h0 512*256][h1 512*256][c0 512*256][c1 512*256]
constexpr int OUT_H = kB * kA;              // 4608
constexpr int OUT_C = OUT_H + 2 * kBH;      // 266752

__device__ __forceinline__ short f2bf(float f) {  // RTNE fp32 -> bf16 bits
  uint32_t u = __float_as_uint(f);
  u += 0x7fffu + ((u >> 16) & 1u);
  return (short)(u >> 16);
}
__device__ __forceinline__ float fast_sigmoid(float v) {
  return __builtin_amdgcn_rcpf(1.f + __expf(-v));
}
__device__ __forceinline__ float fast_tanh(float v) {
  return 2.f * __builtin_amdgcn_rcpf(1.f + __expf(-2.f * v)) - 1.f;
}

// Persistent fused scan, pipeline-skewed (phase p: layer0(p) + layer1(p-1)),
// RELAXED agent-scope exchange (no bulk L2 maintenance), ONE IC round/phase.
// R4 change: block=512 (8 waves, 16 gate-cols/wave) -> ~190 VGPR/wave ->
// 2 waves/SIMD, so LDS/transcendental/MFMA dep-chain stalls overlap across
// waves instead of being fully exposed at 1 wave/SIMD (R3: 71% idle).
__global__ __launch_bounds__(kT, 2) void lstm_scan_kernel(
    const float* __restrict__ x,
    const float* __restrict__ W_emb, const float* __restrict__ b_emb,
    const float* __restrict__ w_ih0, const float* __restrict__ w_hh0,
    const float* __restrict__ b_ih0, const float* __restrict__ b_hh0,
    const float* __restrict__ w_ih1, const float* __restrict__ w_hh1,
    const float* __restrict__ b_ih1, const float* __restrict__ b_hh1,
    unsigned short* __restrict__ h0ex, unsigned short* __restrict__ h1ex,
    int* __restrict__ flags,
    float* __restrict__ dout)
{
  const int tid   = threadIdx.x;
  const int btile = blockIdx.x & (kNB - 1);  // bid%32 -> slices of a btile share an XCD
  const int slice = blockIdx.x >> 5;
  const int b0    = btile * 16;
  const int lane  = tid & 63;
  const int wave  = tid >> 6;                // 0..7 == this wave's N-tile (16 gate cols)
  const int n16   = lane & 15;
  const int quad  = lane >> 4;

  __shared__ short embL[16 * LDH];   // emb(p) (bf16) A-operand
  __shared__ short hA[16 * LDH];     // h0(p-1) — feeds layer0 recurrence AND layer1 input
  __shared__ short hB[16 * LDH];     // h1(p-2) — feeds layer1 recurrence
  __shared__ float gL0[16 * LDG];    // layer0 gates 16 x 128 fp32
  __shared__ float gL1[16 * LDG];    // layer1 gates 16 x 128 fp32

  for (int i = tid; i < 16 * LDH; i += kT) { hA[i] = 0; hB[i] = 0; }

  // Weight B-fragments: this wave owns gate cols [lcol16, +16) where the
  // global gate col = (wave>>1)*256 + slice*32 + (wave&1)*16 + n16.
  // B-frag: lane(n=n16, quad) holds B[k=quad*8+j][n] (weights [4H,H] row-major).
  const float* Wm[4] = { w_ih0, w_hh0, w_ih1, w_hh1 };
  short8 wB[4][8];
  {
    const int gcol = (wave >> 1) * kH + slice * 32 + (wave & 1) * 16 + n16;
#pragma unroll
    for (int mat = 0; mat < 4; ++mat) {
      const float* wp = Wm[mat] + (size_t)gcol * kH;
#pragma unroll
      for (int kk = 0; kk < 8; ++kk) {
        const float* p = wp + kk * 32 + quad * 8;
        const float4 f0 = *(const float4*)p;
        const float4 f1 = *(const float4*)(p + 4);
        short8 v;
        v[0] = f2bf(f0.x); v[1] = f2bf(f0.y); v[2] = f2bf(f0.z); v[3] = f2bf(f0.w);
        v[4] = f2bf(f1.x); v[5] = f2bf(f1.y); v[6] = f2bf(f1.z); v[7] = f2bf(f1.w);
        wB[mat][kk] = v;
      }
    }
  }
  // Embedding weights (K=12 zero-padded to 32). Wave computes emb cols [wave*32, +32).
  short8 wE[2];
  float bembv[2];
#pragma unroll
  for (int i = 0; i < 2; ++i) {
    const int col = wave * 32 + i * 16 + n16;
    short8 v;
#pragma unroll
    for (int j = 0; j < 8; ++j) {
      const int k = quad * 8 + j;
      v[j] = (k < kI) ? f2bf(W_emb[col * kI + k]) : (short)0;
    }
    wE[i] = v;
    bembv[i] = b_emb[col];
  }
  // Elementwise mapping: thread = (row=tid>>5, col=tid&31); 1 hidden unit per layer.
  const int erow = tid >> 5;
  const int ec   = tid & 31;
  const int ecol = slice * 32 + ec;
  float bi0[4], bi1[4];
#pragma unroll
  for (int g = 0; g < 4; ++g) {
    bi0[g] = b_ih0[g * kH + ecol] + b_hh0[g * kH + ecol];
    bi1[g] = b_ih1[g * kH + ecol] + b_hh1[g * kH + ecol];
  }
  float c0v = 0.f, c1v = 0.f;

  // -------- prologue: emb(0) from direct global x loads --------
  {
    const float* xr = x + (size_t)(b0 + n16) * kS * kI;  // t = 0
    short8 xa;
#pragma unroll
    for (int j = 0; j < 8; ++j) {
      const int k = quad * 8 + j;
      xa[j] = (k < kI) ? f2bf(xr[k]) : (short)0;
    }
#pragma unroll
    for (int i = 0; i < 2; ++i) {
      f32x4 z = {0.f, 0.f, 0.f, 0.f};
      f32x4 e = MFMA16(xa, wE[i], z);
      const int col = wave * 32 + i * 16 + n16;
#pragma unroll
      for (int r = 0; r < 4; ++r) {
        float v = e[r] + bembv[i];
        v = v > 0.f ? v : 0.f;
        embL[(quad * 4 + r) * LDH + col] = f2bf(v);  // C-layout: row=quad*4+r
      }
    }
  }
  __syncthreads();

  int* const fl = flags + btile * FLS;

  for (int p = 0; p <= kS; ++p) {
    const int par = p & 1;

    // ---- head: both layers' gates; 32 MFMAs/wave (hA fragments shared).
    //      Edge phases compute don't-care values; state updates are guarded. ----
    {
      f32x4 a0 = {0.f,0.f,0.f,0.f}, g1 = a0;
#pragma unroll
      for (int kk = 0; kk < 8; ++kk) {
        const short8 ha = *(const short8*)&hA[n16 * LDH + kk * 32 + quad * 8];
        a0 = MFMA16(ha, wB[1][kk], a0);   // layer0 recurrent
        g1 = MFMA16(ha, wB[2][kk], g1);   // layer1 input (y0 = h0(p-1))
      }
#pragma unroll
      for (int kk = 0; kk < 8; ++kk) {
        const short8 e = *(const short8*)&embL[n16 * LDH + kk * 32 + quad * 8];
        a0 = MFMA16(e, wB[0][kk], a0);    // layer0 input
      }
#pragma unroll
      for (int kk = 0; kk < 8; ++kk) {
        const short8 hb = *(const short8*)&hB[n16 * LDH + kk * 32 + quad * 8];
        g1 = MFMA16(hb, wB[3][kk], g1);   // layer1 recurrent
      }
      const int lcol = (wave >> 1) * 32 + (wave & 1) * 16 + n16;
#pragma unroll
      for (int r = 0; r < 4; ++r) {
        gL0[(quad * 4 + r) * LDG + lcol] = a0[r];
        gL1[(quad * 4 + r) * LDG + lcol] = g1[r];
      }
    }
    __syncthreads();  // B1: gate tiles ready

    // ---- elementwise layer0 (step p), guarded ----
    if (p < kS) {
      const float iv = gL0[erow * LDG +       ec] + bi0[0];
      const float fv = gL0[erow * LDG +  32 + ec] + bi0[1];
      const float gv = gL0[erow * LDG +  64 + ec] + bi0[2];
      const float ov = gL0[erow * LDG +  96 + ec] + bi0[3];
      const float c = fast_sigmoid(fv) * c0v + fast_sigmoid(iv) * fast_tanh(gv);
      c0v = c;
      const float h = fast_sigmoid(ov) * fast_tanh(c);
      unsigned short* dst = &h0ex[(size_t)par * kBH + (size_t)(b0 + erow) * kH + ecol];
      __hip_atomic_store(dst, (unsigned short)f2bf(h), __ATOMIC_RELAXED, __HIP_MEMORY_SCOPE_AGENT);
      if (p == kS - 1) {
        dout[OUT_H + (size_t)(b0 + erow) * kH + ecol] = h;
        dout[OUT_C + (size_t)(b0 + erow) * kH + ecol] = c;
      }
    }
    // ---- elementwise layer1 (step p-1), guarded ----
    if (p >= 1) {
      const float iv = gL1[erow * LDG +       ec] + bi1[0];
      const float fv = gL1[erow * LDG +  32 + ec] + bi1[1];
      const float gv = gL1[erow * LDG +  64 + ec] + bi1[2];
      const float ov = gL1[erow * LDG +  96 + ec] + bi1[3];
      const float c = fast_sigmoid(fv) * c1v + fast_sigmoid(iv) * fast_tanh(gv);
      c1v = c;
      const float h = fast_sigmoid(ov) * fast_tanh(c);
      unsigned short* dst = &h1ex[(size_t)par * kBH + (size_t)(b0 + erow) * kH + ecol];
      __hip_atomic_store(dst, (unsigned short)f2bf(h), __ATOMIC_RELAXED, __HIP_MEMORY_SCOPE_AGENT);
      if (p == kS) {
        dout[OUT_H + kBH + (size_t)(b0 + erow) * kH + ecol] = h;
        dout[OUT_C + kBH + (size_t)(b0 + erow) * kH + ecol] = c;
      }
    }
    __syncthreads();  // B2: drains vmcnt(0) -> exchange stores IC-visible

    if (p < kS) {
      // ---- publish (single flag covers h0(p) AND h1(p-1)) ----
      if (tid == 0)
        __hip_atomic_fetch_add(fl + p, 1, __ATOMIC_RELAXED, __HIP_MEMORY_SCOPE_AGENT);

      // ---- emb(p+1): overlaps flag/data propagation through the IC ----
      if (p + 1 < kS) {
        const float* xr = x + ((size_t)(b0 + n16) * kS + (p + 1)) * kI;
        short8 xa;
#pragma unroll
        for (int j = 0; j < 8; ++j) {
          const int k = quad * 8 + j;
          xa[j] = (k < kI) ? f2bf(xr[k]) : (short)0;
        }
#pragma unroll
        for (int i = 0; i < 2; ++i) {
          f32x4 z = {0.f, 0.f, 0.f, 0.f};
          f32x4 e = MFMA16(xa, wE[i], z);
          const int col = wave * 32 + i * 16 + n16;
#pragma unroll
          for (int r = 0; r < 4; ++r) {
            float v = e[r] + bembv[i];
            v = v > 0.f ? v : 0.f;
            embL[(quad * 4 + r) * LDH + col] = f2bf(v);
          }
        }
      }

      // ---- all-thread spin (uniform exit) ----
      while (__hip_atomic_load(fl + p, __ATOMIC_RELAXED, __HIP_MEMORY_SCOPE_AGENT) < kNS)
        __builtin_amdgcn_s_sleep(1);

      // ---- gather h0(p) -> hA, h1(p-1) -> hB (relaxed u64 loads) ----
      {
        const int rr = tid >> 5;
        const int cc = (tid & 31) * 8;
        const size_t base = (size_t)par * kBH + (size_t)(b0 + rr) * kH + cc;
        const uint64_t* s0 = (const uint64_t*)&h0ex[base];
        const uint64_t* s1 = (const uint64_t*)&h1ex[base];
        uint64_t va0 = __hip_atomic_load(s0 + 0, __ATOMIC_RELAXED, __HIP_MEMORY_SCOPE_AGENT);
        uint64_t va1 = __hip_atomic_load(s0 + 1, __ATOMIC_RELAXED, __HIP_MEMORY_SCOPE_AGENT);
        uint64_t vb0 = __hip_atomic_load(s1 + 0, __ATOMIC_RELAXED, __HIP_MEMORY_SCOPE_AGENT);
        uint64_t vb1 = __hip_atomic_load(s1 + 1, __ATOMIC_RELAXED, __HIP_MEMORY_SCOPE_AGENT);
        uint64_t* dA = (uint64_t*)&hA[rr * LDH + cc];
        uint64_t* dB = (uint64_t*)&hB[rr * LDH + cc];
        dA[0] = va0; dA[1] = va1;
        dB[0] = vb0; dB[1] = vb1;
      }
      __syncthreads();  // B5: hA/hB/embL ready for next phase's head
    }
  }
}

// LayerNorm + MLP head, exact fp32. One wave per batch row.
__global__ __launch_bounds__(64) void head_kernel(
    const float* __restrict__ h1last, const float* __restrict__ mask,
    const float* __restrict__ ln_g, const float* __restrict__ ln_b,
    const float* __restrict__ w1, const float* __restrict__ b1,
    const float* __restrict__ w2, const float* __restrict__ b2,
    float* __restrict__ out)
{
  const int r = blockIdx.x;
  const int lane = threadIdx.x;
  __shared__ float ns[kH];
  __shared__ float hd[32];
  const float4 v = *(const float4*)&h1last[r * kH + lane * 4];
  float vv[4] = {v.x, v.y, v.z, v.w};
  float s = vv[0] + vv[1] + vv[2] + vv[3];
#pragma unroll
  for (int off = 32; off > 0; off >>= 1) s += __shfl_xor(s, off, 64);
  const float mean = s * (1.f / kH);
  float q = 0.f;
#pragma unroll
  for (int j = 0; j < 4; ++j) { const float d = vv[j] - mean; q += d * d; }
#pragma unroll
  for (int off = 32; off > 0; off >>= 1) q += __shfl_xor(q, off, 64);
  const float rstd = rsqrtf(q * (1.f / kH) + 1e-5f);
#pragma unroll
  for (int j = 0; j < 4; ++j) {
    const int c = lane * 4 + j;
    ns[c] = (vv[j] - mean) * rstd * ln_g[c] + ln_b[c];
  }
  __syncthreads();
  if (lane < 32) {
    float a = b1[lane];
    const float* wr = w1 + lane * kH;
    for (int k = 0; k < kH; ++k) a += ns[k] * wr[k];
    hd[lane] = a > 0.f ? a : 0.f;
  }
  __syncthreads();
  if (lane < kA) {
    float a = b2[lane];
    const float* wr = w2 + lane * 32;
#pragma unroll
    for (int k = 0; k < 32; ++k) a += hd[k] * wr[k];
    a += (1.f - mask[r * kA + lane]) * (-1e9f);
    out[r * kA + lane] = a;
  }
}

extern "C" void kernel_launch(void* const* d_in, const int* in_sizes, int n_in,
                              void* d_out, int out_size, void* d_ws, size_t ws_size,
                              hipStream_t stream)
{
  (void)in_sizes; (void)n_in; (void)out_size; (void)ws_size;
  const float* x     = (const float*)d_in[0];
  const float* mask  = (const float*)d_in[1];
  const float* W_emb = (const float*)d_in[2];
  const float* b_emb = (const float*)d_in[3];
  const float* w_ih0 = (const float*)d_in[4];
  const float* w_hh0 = (const float*)d_in[5];
  const float* b_ih0 = (const float*)d_in[6];
  const float* b_hh0 = (const float*)d_in[7];
  const float* w_ih1 = (const float*)d_in[8];
  const float* w_hh1 = (const float*)d_in[9];
  const float* b_ih1 = (const float*)d_in[10];
  const float* b_hh1 = (const float*)d_in[11];
  const float* ln_g  = (const float*)d_in[12];
  const float* ln_b  = (const float*)d_in[13];
  const float* w1    = (const float*)d_in[14];
  const float* b1    = (const float*)d_in[15];
  const float* w2    = (const float*)d_in[16];
  const float* b2    = (const float*)d_in[17];
  float* out = (float*)d_out;

  // ws layout: h0ex[2][512][256] bf16 | h1ex[2][512][256] bf16 | flags[32][512] int
  unsigned short* h0ex = (unsigned short*)d_ws;
  unsigned short* h1ex = h0ex + 2 * kBH;
  int* flags = (int*)(h1ex + 2 * kBH);
  const size_t flag_bytes = (size_t)kNB * FLS * sizeof(int);  // 64 KiB

  // flags must start 0; h1ex parity-0 must be zeros (h1(-1)=0, gathered at p=0).
  hipMemsetAsync(flags, 0, flag_bytes, stream);
  hipMemsetAsync(h1ex, 0, (size_t)kBH * sizeof(unsigned short), stream);

  lstm_scan_kernel<<<dim3(kNB * kNS), dim3(kT), 0, stream>>>(
      x, W_emb, b_emb, w_ih0, w_hh0, b_ih0, b_hh0, w_ih1, w_hh1, b_ih1, b_hh1,
      h0ex, h1ex, flags, out);

  head_kernel<<<dim3(kB), dim3(64), 0, stream>>>(
      out + OUT_H + kBH, mask, ln_g, ln_b, w1, b1, w2, b2, out);
}